// Round 3
// baseline (704.577 us; speedup 1.0000x reference)
//
#include <hip/hip_runtime.h>

constexpr int D_IN  = 64;
constexpr int D_H1  = 32;
constexpr int D_H2  = 64;
constexpr int D_OUT = 128;
constexpr int NSEG  = 8192;

constexpr int BLOCK = 256;       // 4 waves
constexpr int RT    = 64;        // rows per tile (== wave size: ballot covers tile)
constexpr int TPB   = 8;         // tiles per block
constexpr int SYS   = 132;       // sy row stride in bf16 (pad breaks conflicts)

typedef __bf16 bfx8 __attribute__((ext_vector_type(8)));
typedef __bf16 bfx4 __attribute__((ext_vector_type(4)));
typedef float  fx4  __attribute__((ext_vector_type(4)));

// MFMA 16x16x32 bf16 layouts (m89-verified):
//   A: m = lane&15, k = (lane>>4)*8 + j
//   B: n = lane&15, k = (lane>>4)*8 + i
//   D: row(m) = (lane>>4)*4 + reg, col(n) = lane&15

__global__ __launch_bounds__(BLOCK, 4) void mlp_seg_mfma(
    const float* __restrict__ f, const int* __restrict__ seg,
    const float* __restrict__ W1, const float* __restrict__ b1,
    const float* __restrict__ W2, const float* __restrict__ b2,
    const float* __restrict__ W3, const float* __restrict__ b3,
    float* __restrict__ sums, float* __restrict__ counts,
    int N, int ntiles)
{
    __shared__ __align__(16) __bf16 sf [RT * 64];    // 8 KB (XOR-swizzled)
    __shared__ __align__(16) __bf16 sh1[RT * 32];    // 4 KB
    __shared__ __align__(16) __bf16 sh2[RT * 64];    // 8 KB
    __shared__ __align__(16) __bf16 sy [RT * SYS];   // 16.9 KB
    __shared__ float pbuf[4 * 128];                  // 2 KB (h=1 partials)
    __shared__ int sseg[RT];

    const int tid  = threadIdx.x;
    const int wv   = tid >> 6;
    const int lane = tid & 63;
    const int lr   = lane & 15;
    const int quad = lane >> 4;
    const int m0   = wv * 16;
    const int ar   = m0 + lr;

    // ---- weight B-fragments + biases -> registers ----
    bfx8 fw1[2][2];
    #pragma unroll
    for (int j = 0; j < 2; ++j)
        #pragma unroll
        for (int ks = 0; ks < 2; ++ks)
            #pragma unroll
            for (int i = 0; i < 8; ++i)
                fw1[j][ks][i] = (__bf16)W1[(ks*32 + quad*8 + i)*D_H1 + j*16 + lr];

    bfx8 fw2[4];
    #pragma unroll
    for (int j = 0; j < 4; ++j)
        #pragma unroll
        for (int i = 0; i < 8; ++i)
            fw2[j][i] = (__bf16)W2[(quad*8 + i)*D_H2 + j*16 + lr];

    bfx8 fw3[8][2];
    #pragma unroll
    for (int j = 0; j < 8; ++j)
        #pragma unroll
        for (int ks = 0; ks < 2; ++ks)
            #pragma unroll
            for (int i = 0; i < 8; ++i)
                fw3[j][ks][i] = (__bf16)W3[(ks*32 + quad*8 + i)*D_OUT + j*16 + lr];

    float rb1[2], rb2[4], rb3[8];
    #pragma unroll
    for (int j = 0; j < 2; ++j) rb1[j] = b1[j*16 + lr];
    #pragma unroll
    for (int j = 0; j < 4; ++j) rb2[j] = b2[j*16 + lr];
    #pragma unroll
    for (int j = 0; j < 8; ++j) rb3[j] = b3[j*16 + lr];

    // ---- persistent per-column run state (h==0 threads, i.e. waves 0-1) ----
    const int col = tid & 127;
    const int hh  = tid >> 7;          // row-half owned in the reduce phase
    int   cur_seg = -1;
    float run_sum = 0.f;
    int   run_cnt = 0;

    const int t0 = blockIdx.x * TPB;
    const int t1 = min(t0 + TPB, ntiles);

    // ---- prefetch tile t0 into registers ----
    float4 q[4];
    int segv = -2;
    {
        const size_t base4 = (size_t)t0 * RT * 16;
        const float4* f4 = (const float4*)f;
        #pragma unroll
        for (int i = 0; i < 4; ++i) {
            const int idx4 = tid + i * 256;
            q[i] = make_float4(0.f, 0.f, 0.f, 0.f);
            if ((base4 + idx4) * 4 < (size_t)N * 64) q[i] = f4[base4 + idx4];
        }
        if (tid < RT) segv = (t0 * RT + tid < N) ? seg[t0 * RT + tid] : -2;
    }

    for (int t = t0; t < t1; ++t) {
        // ---- stage current tile from regs -> bf16 -> swizzled LDS ----
        #pragma unroll
        for (int i = 0; i < 4; ++i) {
            const int idx4 = tid + i * 256;
            const int r = idx4 >> 4;
            const int c = (idx4 & 15) * 4;
            bfx4 v;
            v[0] = (__bf16)q[i].x; v[1] = (__bf16)q[i].y;
            v[2] = (__bf16)q[i].z; v[3] = (__bf16)q[i].w;
            const int pe = r*64 + ((((c >> 3) ^ (r & 7))) << 3) + (c & 7);
            *(bfx4*)&sf[pe] = v;
        }
        if (tid < RT) sseg[tid] = segv;
        __syncthreads();                                   // B1: sf/sseg ready

        // ---- issue prefetch for tile t+1 (overlaps all compute below) ----
        if (t + 1 < t1) {
            const size_t base4 = (size_t)(t + 1) * RT * 16;
            const float4* f4 = (const float4*)f;
            #pragma unroll
            for (int i = 0; i < 4; ++i) {
                const int idx4 = tid + i * 256;
                q[i] = make_float4(0.f, 0.f, 0.f, 0.f);
                if ((base4 + idx4) * 4 < (size_t)N * 64) q[i] = f4[base4 + idx4];
            }
            if (tid < RT) segv = ((t+1) * RT + tid < N) ? seg[(t+1) * RT + tid] : -2;
        }

        // ---- L1: [16,64]@[64,32] per wave ----
        fx4 acc1[2] = {{0,0,0,0},{0,0,0,0}};
        #pragma unroll
        for (int ks = 0; ks < 2; ++ks) {
            bfx8 a = *(const bfx8*)&sf[ar*64 + (((ks*4 + quad) ^ (ar & 7)) << 3)];
            #pragma unroll
            for (int j = 0; j < 2; ++j)
                acc1[j] = __builtin_amdgcn_mfma_f32_16x16x32_bf16(a, fw1[j][ks], acc1[j], 0, 0, 0);
        }
        #pragma unroll
        for (int j = 0; j < 2; ++j)
            #pragma unroll
            for (int rg = 0; rg < 4; ++rg) {
                const int row = m0 + quad*4 + rg;
                const int cc  = j*16 + lr;
                const float v = fmaxf(acc1[j][rg] + rb1[j], 0.f);
                sh1[row*32 + (((cc >> 3) ^ (row & 3)) << 3) + (cc & 7)] = (__bf16)v;
            }
        // no barrier: sh1 rows [m0,m0+16) are private to this wave

        // ---- L2: [16,32]@[32,64] ----
        fx4 acc2[4] = {{0,0,0,0},{0,0,0,0},{0,0,0,0},{0,0,0,0}};
        {
            bfx8 a = *(const bfx8*)&sh1[ar*32 + ((quad ^ (ar & 3)) << 3)];
            #pragma unroll
            for (int j = 0; j < 4; ++j)
                acc2[j] = __builtin_amdgcn_mfma_f32_16x16x32_bf16(a, fw2[j], acc2[j], 0, 0, 0);
        }
        #pragma unroll
        for (int j = 0; j < 4; ++j)
            #pragma unroll
            for (int rg = 0; rg < 4; ++rg) {
                const int row = m0 + quad*4 + rg;
                const int cc  = j*16 + lr;
                const float v = fmaxf(acc2[j][rg] + rb2[j], 0.f);
                sh2[row*64 + (((cc >> 3) ^ (row & 7)) << 3) + (cc & 7)] = (__bf16)v;
            }

        // ---- L3: [16,64]@[64,128] in two halves (caps VGPR) -> sy ----
        #pragma unroll
        for (int h = 0; h < 2; ++h) {
            fx4 acc3[4] = {{0,0,0,0},{0,0,0,0},{0,0,0,0},{0,0,0,0}};
            #pragma unroll
            for (int ks = 0; ks < 2; ++ks) {
                bfx8 a = *(const bfx8*)&sh2[ar*64 + (((ks*4 + quad) ^ (ar & 7)) << 3)];
                #pragma unroll
                for (int j = 0; j < 4; ++j)
                    acc3[j] = __builtin_amdgcn_mfma_f32_16x16x32_bf16(a, fw3[h*4 + j][ks], acc3[j], 0, 0, 0);
            }
            #pragma unroll
            for (int j = 0; j < 4; ++j)
                #pragma unroll
                for (int rg = 0; rg < 4; ++rg) {
                    const int row = m0 + quad*4 + rg;
                    const int cc  = (h*4 + j)*16 + lr;
                    sy[row*SYS + cc] = (__bf16)(acc3[j][rg] + rb3[h*4 + j]);
                }
        }
        __syncthreads();                                   // B2: sy ready

        // ---- segment boundaries for this tile (per-wave ballot, RT==64) ----
        const int prev = (lane == 0) ? -999999 : sseg[lane - 1];
        const unsigned long long bmask = __ballot(sseg[lane] != prev);
        const int nuniq = __popcll(bmask);

        // ---- parallel contiguous-range reduction + persistent run state ----
        unsigned long long mrem = bmask;
        for (int base = 0; base < nuniq; base += 4) {
            const int nk = min(4, nuniq - base);
            float pk[4]; int sk[4]; int ck[4];
            unsigned long long mit = mrem;
            for (int k = 0; k < nk; ++k) {
                const int st = __ffsll((long long)mit) - 1;
                const unsigned long long mnx = mit & (mit - 1);
                const int en = mnx ? (__ffsll((long long)mnx) - 1) : RT;
                sk[k] = sseg[st];
                ck[k] = en - st;
                const int lo = max(st, hh * 32);
                const int hi = min(en, hh * 32 + 32);
                float a0 = 0.f, a1 = 0.f;
                for (int r = lo; r < hi; r += 2) {
                    a0 += (float)sy[r * SYS + col];
                    if (r + 1 < hi) a1 += (float)sy[(r + 1) * SYS + col];
                }
                pk[k] = a0 + a1;
                mit = mnx;
            }
            mrem = mit;
            if (hh == 1) {
                for (int k = 0; k < nk; ++k) pbuf[k * 128 + col] = pk[k];
            }
            __syncthreads();                               // B3: pbuf ready
            if (hh == 0) {
                for (int k = 0; k < nk; ++k) {
                    const int s = sk[k];
                    const float val = pk[k] + pbuf[k * 128 + col];
                    if (s != cur_seg) {
                        if (cur_seg >= 0) {
                            atomicAdd(&sums[(size_t)cur_seg * D_OUT + col], run_sum);
                            if (col == 0) atomicAdd(&counts[cur_seg], (float)run_cnt);
                        }
                        cur_seg = s; run_sum = 0.f; run_cnt = 0;
                    }
                    run_sum += val; run_cnt += ck[k];
                }
            }
            if (base + 4 < nuniq) __syncthreads();         // protect pbuf reuse
        }
        // no trailing barrier needed: h==1 threads only touch sf/sseg next,
        // which h==0 threads are done reading; B1 re-syncs everyone.
    }

    if (hh == 0 && cur_seg >= 0) {
        atomicAdd(&sums[(size_t)cur_seg * D_OUT + col], run_sum);
        if (col == 0) atomicAdd(&counts[cur_seg], (float)run_cnt);
    }
}

__global__ __launch_bounds__(256) void div_kernel(
    const float* __restrict__ sums, const float* __restrict__ counts,
    float* __restrict__ out, int total)
{
    const int i = blockIdx.x * 256 + threadIdx.x;
    if (i < total) out[i] = sums[i] / fmaxf(counts[i >> 7], 1.f);
}

extern "C" void kernel_launch(void* const* d_in, const int* in_sizes, int n_in,
                              void* d_out, int out_size, void* d_ws, size_t ws_size,
                              hipStream_t stream) {
    const float* f   = (const float*)d_in[0];
    const int*   seg = (const int*)  d_in[1];
    const float* W1 = (const float*)d_in[3];
    const float* b1 = (const float*)d_in[4];
    const float* W2 = (const float*)d_in[5];
    const float* b2 = (const float*)d_in[6];
    const float* W3 = (const float*)d_in[7];
    const float* b3 = (const float*)d_in[8];
    float* out = (float*)d_out;

    const int N = in_sizes[0] / D_IN;

    float* sums   = (float*)d_ws;
    float* counts = sums + (size_t)NSEG * D_OUT;

    hipMemsetAsync(d_ws, 0, ((size_t)NSEG * D_OUT + NSEG) * sizeof(float), stream);

    const int ntiles  = (N + RT - 1) / RT;
    const int nblocks = (ntiles + TPB - 1) / TPB;
    mlp_seg_mfma<<<nblocks, BLOCK, 0, stream>>>(f, seg, W1, b1, W2, b2, W3, b3,
                                                sums, counts, N, ntiles);

    const int total = NSEG * D_OUT;
    div_kernel<<<(total + 255) / 256, 256, 0, stream>>>(sums, counts, out, total);
}

// Round 4
// 578.889 us; speedup vs baseline: 1.2171x; 1.2171x over previous
//
#include <hip/hip_runtime.h>

constexpr int D_IN  = 64;
constexpr int D_H1  = 32;
constexpr int D_H2  = 64;
constexpr int D_OUT = 128;
constexpr int NSEG  = 8192;

constexpr int BLOCK = 256;       // 4 waves
constexpr int RT    = 64;        // rows per tile (== wave size: ballot covers tile)
constexpr int TPB   = 8;         // tiles per block
constexpr int SYS   = 132;       // sy row stride in bf16 (pad breaks conflicts)

typedef __bf16 bfx8 __attribute__((ext_vector_type(8)));
typedef __bf16 bfx4 __attribute__((ext_vector_type(4)));
typedef float  fx4  __attribute__((ext_vector_type(4)));

// MFMA 16x16x32 bf16 layouts (m89-verified):
//   A: m = lane&15, k = (lane>>4)*8 + j
//   B: n = lane&15, k = (lane>>4)*8 + i
//   D: row(m) = (lane>>4)*4 + reg, col(n) = lane&15

// NOTE: min-waves=3 (cap ~170 VGPR). Round 3 used 4 (cap 128) and the ~96
// register-resident weight VGPRs spilled to scratch: +1.0 GB HBM traffic,
// 2x regression. Do not tighten this without shrinking the live set.
__global__ __launch_bounds__(BLOCK, 3) void mlp_seg_mfma(
    const float* __restrict__ f, const int* __restrict__ seg,
    const float* __restrict__ W1, const float* __restrict__ b1,
    const float* __restrict__ W2, const float* __restrict__ b2,
    const float* __restrict__ W3, const float* __restrict__ b3,
    float* __restrict__ sums, float* __restrict__ counts,
    int N, int ntiles)
{
    __shared__ __align__(16) __bf16 sf [RT * 64];    // 8 KB (XOR-swizzled)
    __shared__ __align__(16) __bf16 sh1[RT * 32];    // 4 KB
    __shared__ __align__(16) __bf16 sh2[RT * 64];    // 8 KB
    __shared__ __align__(16) __bf16 sy [RT * SYS];   // 16.9 KB
    __shared__ float pbuf[4 * 128];                  // 2 KB (h=1 partials)
    __shared__ int sseg[RT];

    const int tid  = threadIdx.x;
    const int wv   = tid >> 6;
    const int lane = tid & 63;
    const int lr   = lane & 15;
    const int quad = lane >> 4;
    const int m0   = wv * 16;
    const int ar   = m0 + lr;

    // ---- weight B-fragments + biases -> registers ----
    bfx8 fw1[2][2];
    #pragma unroll
    for (int j = 0; j < 2; ++j)
        #pragma unroll
        for (int ks = 0; ks < 2; ++ks)
            #pragma unroll
            for (int i = 0; i < 8; ++i)
                fw1[j][ks][i] = (__bf16)W1[(ks*32 + quad*8 + i)*D_H1 + j*16 + lr];

    bfx8 fw2[4];
    #pragma unroll
    for (int j = 0; j < 4; ++j)
        #pragma unroll
        for (int i = 0; i < 8; ++i)
            fw2[j][i] = (__bf16)W2[(quad*8 + i)*D_H2 + j*16 + lr];

    bfx8 fw3[8][2];
    #pragma unroll
    for (int j = 0; j < 8; ++j)
        #pragma unroll
        for (int ks = 0; ks < 2; ++ks)
            #pragma unroll
            for (int i = 0; i < 8; ++i)
                fw3[j][ks][i] = (__bf16)W3[(ks*32 + quad*8 + i)*D_OUT + j*16 + lr];

    float rb1[2], rb2[4], rb3[8];
    #pragma unroll
    for (int j = 0; j < 2; ++j) rb1[j] = b1[j*16 + lr];
    #pragma unroll
    for (int j = 0; j < 4; ++j) rb2[j] = b2[j*16 + lr];
    #pragma unroll
    for (int j = 0; j < 8; ++j) rb3[j] = b3[j*16 + lr];

    // ---- persistent per-column run state (h==0 threads, i.e. waves 0-1) ----
    const int col = tid & 127;
    const int hh  = tid >> 7;          // row-half owned in the reduce phase
    int   cur_seg = -1;
    float run_sum = 0.f;
    int   run_cnt = 0;

    const int t0 = blockIdx.x * TPB;
    const int t1 = min(t0 + TPB, ntiles);

    // ---- prefetch tile t0 into registers ----
    float4 q[4];
    int segv = -2;
    {
        const size_t base4 = (size_t)t0 * RT * 16;
        const float4* f4 = (const float4*)f;
        #pragma unroll
        for (int i = 0; i < 4; ++i) {
            const int idx4 = tid + i * 256;
            q[i] = make_float4(0.f, 0.f, 0.f, 0.f);
            if ((base4 + idx4) * 4 < (size_t)N * 64) q[i] = f4[base4 + idx4];
        }
        if (tid < RT) segv = (t0 * RT + tid < N) ? seg[t0 * RT + tid] : -2;
    }

    for (int t = t0; t < t1; ++t) {
        // ---- stage current tile from regs -> bf16 -> swizzled LDS ----
        #pragma unroll
        for (int i = 0; i < 4; ++i) {
            const int idx4 = tid + i * 256;
            const int r = idx4 >> 4;
            const int c = (idx4 & 15) * 4;
            bfx4 v;
            v[0] = (__bf16)q[i].x; v[1] = (__bf16)q[i].y;
            v[2] = (__bf16)q[i].z; v[3] = (__bf16)q[i].w;
            const int pe = r*64 + ((((c >> 3) ^ (r & 7))) << 3) + (c & 7);
            *(bfx4*)&sf[pe] = v;
        }
        if (tid < RT) sseg[tid] = segv;
        __syncthreads();                                   // B1: sf/sseg ready

        // ---- issue prefetch for tile t+1 (overlaps all compute below) ----
        if (t + 1 < t1) {
            const size_t base4 = (size_t)(t + 1) * RT * 16;
            const float4* f4 = (const float4*)f;
            #pragma unroll
            for (int i = 0; i < 4; ++i) {
                const int idx4 = tid + i * 256;
                q[i] = make_float4(0.f, 0.f, 0.f, 0.f);
                if ((base4 + idx4) * 4 < (size_t)N * 64) q[i] = f4[base4 + idx4];
            }
            if (tid < RT) segv = ((t+1) * RT + tid < N) ? seg[(t+1) * RT + tid] : -2;
        }

        // ---- L1: [16,64]@[64,32] per wave ----
        fx4 acc1[2] = {{0,0,0,0},{0,0,0,0}};
        #pragma unroll
        for (int ks = 0; ks < 2; ++ks) {
            bfx8 a = *(const bfx8*)&sf[ar*64 + (((ks*4 + quad) ^ (ar & 7)) << 3)];
            #pragma unroll
            for (int j = 0; j < 2; ++j)
                acc1[j] = __builtin_amdgcn_mfma_f32_16x16x32_bf16(a, fw1[j][ks], acc1[j], 0, 0, 0);
        }
        #pragma unroll
        for (int j = 0; j < 2; ++j)
            #pragma unroll
            for (int rg = 0; rg < 4; ++rg) {
                const int row = m0 + quad*4 + rg;
                const int cc  = j*16 + lr;
                const float v = fmaxf(acc1[j][rg] + rb1[j], 0.f);
                sh1[row*32 + (((cc >> 3) ^ (row & 3)) << 3) + (cc & 7)] = (__bf16)v;
            }
        // no barrier: sh1 rows [m0,m0+16) are private to this wave

        // ---- L2: [16,32]@[32,64] ----
        fx4 acc2[4] = {{0,0,0,0},{0,0,0,0},{0,0,0,0},{0,0,0,0}};
        {
            bfx8 a = *(const bfx8*)&sh1[ar*32 + ((quad ^ (ar & 3)) << 3)];
            #pragma unroll
            for (int j = 0; j < 4; ++j)
                acc2[j] = __builtin_amdgcn_mfma_f32_16x16x32_bf16(a, fw2[j], acc2[j], 0, 0, 0);
        }
        #pragma unroll
        for (int j = 0; j < 4; ++j)
            #pragma unroll
            for (int rg = 0; rg < 4; ++rg) {
                const int row = m0 + quad*4 + rg;
                const int cc  = j*16 + lr;
                const float v = fmaxf(acc2[j][rg] + rb2[j], 0.f);
                sh2[row*64 + (((cc >> 3) ^ (row & 7)) << 3) + (cc & 7)] = (__bf16)v;
            }

        // ---- L3: [16,64]@[64,128] in two halves (caps VGPR) -> sy ----
        #pragma unroll
        for (int h = 0; h < 2; ++h) {
            fx4 acc3[4] = {{0,0,0,0},{0,0,0,0},{0,0,0,0},{0,0,0,0}};
            #pragma unroll
            for (int ks = 0; ks < 2; ++ks) {
                bfx8 a = *(const bfx8*)&sh2[ar*64 + (((ks*4 + quad) ^ (ar & 7)) << 3)];
                #pragma unroll
                for (int j = 0; j < 4; ++j)
                    acc3[j] = __builtin_amdgcn_mfma_f32_16x16x32_bf16(a, fw3[h*4 + j][ks], acc3[j], 0, 0, 0);
            }
            #pragma unroll
            for (int j = 0; j < 4; ++j)
                #pragma unroll
                for (int rg = 0; rg < 4; ++rg) {
                    const int row = m0 + quad*4 + rg;
                    const int cc  = (h*4 + j)*16 + lr;
                    sy[row*SYS + cc] = (__bf16)(acc3[j][rg] + rb3[h*4 + j]);
                }
        }
        __syncthreads();                                   // B2: sy ready

        // ---- segment boundaries for this tile (per-wave ballot, RT==64) ----
        const int prev = (lane == 0) ? -999999 : sseg[lane - 1];
        const unsigned long long bmask = __ballot(sseg[lane] != prev);
        const int nuniq = __popcll(bmask);

        // ---- parallel contiguous-range reduction + persistent run state ----
        unsigned long long mrem = bmask;
        for (int base = 0; base < nuniq; base += 4) {
            const int nk = min(4, nuniq - base);
            float pk[4]; int sk[4]; int ck[4];
            unsigned long long mit = mrem;
            for (int k = 0; k < nk; ++k) {
                const int st = __ffsll((long long)mit) - 1;
                const unsigned long long mnx = mit & (mit - 1);
                const int en = mnx ? (__ffsll((long long)mnx) - 1) : RT;
                sk[k] = sseg[st];
                ck[k] = en - st;
                const int lo = max(st, hh * 32);
                const int hi = min(en, hh * 32 + 32);
                float a0 = 0.f, a1 = 0.f;
                for (int r = lo; r < hi; r += 2) {
                    a0 += (float)sy[r * SYS + col];
                    if (r + 1 < hi) a1 += (float)sy[(r + 1) * SYS + col];
                }
                pk[k] = a0 + a1;
                mit = mnx;
            }
            mrem = mit;
            if (hh == 1) {
                for (int k = 0; k < nk; ++k) pbuf[k * 128 + col] = pk[k];
            }
            __syncthreads();                               // B3: pbuf ready
            if (hh == 0) {
                for (int k = 0; k < nk; ++k) {
                    const int s = sk[k];
                    const float val = pk[k] + pbuf[k * 128 + col];
                    if (s != cur_seg) {
                        if (cur_seg >= 0) {
                            atomicAdd(&sums[(size_t)cur_seg * D_OUT + col], run_sum);
                            if (col == 0) atomicAdd(&counts[cur_seg], (float)run_cnt);
                        }
                        cur_seg = s; run_sum = 0.f; run_cnt = 0;
                    }
                    run_sum += val; run_cnt += ck[k];
                }
            }
            if (base + 4 < nuniq) __syncthreads();         // protect pbuf reuse
        }
        // no trailing barrier needed: h==1 threads only touch sf/sseg next,
        // which h==0 threads are done reading; B1 re-syncs everyone.
    }

    if (hh == 0 && cur_seg >= 0) {
        atomicAdd(&sums[(size_t)cur_seg * D_OUT + col], run_sum);
        if (col == 0) atomicAdd(&counts[cur_seg], (float)run_cnt);
    }
}

__global__ __launch_bounds__(256) void div_kernel(
    const float* __restrict__ sums, const float* __restrict__ counts,
    float* __restrict__ out, int total)
{
    const int i = blockIdx.x * 256 + threadIdx.x;
    if (i < total) out[i] = sums[i] / fmaxf(counts[i >> 7], 1.f);
}

extern "C" void kernel_launch(void* const* d_in, const int* in_sizes, int n_in,
                              void* d_out, int out_size, void* d_ws, size_t ws_size,
                              hipStream_t stream) {
    const float* f   = (const float*)d_in[0];
    const int*   seg = (const int*)  d_in[1];
    const float* W1 = (const float*)d_in[3];
    const float* b1 = (const float*)d_in[4];
    const float* W2 = (const float*)d_in[5];
    const float* b2 = (const float*)d_in[6];
    const float* W3 = (const float*)d_in[7];
    const float* b3 = (const float*)d_in[8];
    float* out = (float*)d_out;

    const int N = in_sizes[0] / D_IN;

    float* sums   = (float*)d_ws;
    float* counts = sums + (size_t)NSEG * D_OUT;

    hipMemsetAsync(d_ws, 0, ((size_t)NSEG * D_OUT + NSEG) * sizeof(float), stream);

    const int ntiles  = (N + RT - 1) / RT;
    const int nblocks = (ntiles + TPB - 1) / TPB;
    mlp_seg_mfma<<<nblocks, BLOCK, 0, stream>>>(f, seg, W1, b1, W2, b2, W3, b3,
                                                sums, counts, N, ntiles);

    const int total = NSEG * D_OUT;
    div_kernel<<<(total + 255) / 256, 256, 0, stream>>>(sums, counts, out, total);
}